// Round 12
// baseline (679.394 us; speedup 1.0000x reference)
//
#include <hip/hip_runtime.h>
#include <hip/hip_bf16.h>
#include <stdint.h>

// Problem constants (fixed by setup_inputs)
#define B_   64
#define H_   512
#define W_   512
#define S_N  1024      // n_segments
#define E_N  768       // embed_dim
#define K_N  768       // C*box*box = 3*16*16
#define HALF 8

typedef short bf16x8 __attribute__((ext_vector_type(8)));
typedef float f32x4  __attribute__((ext_vector_type(4)));

__device__ __forceinline__ unsigned short f2bf(float f) {
  union { float f; unsigned u; } v; v.f = f;
  unsigned u = v.u;
  u += 0x7FFF + ((u >> 16) & 1);   // RNE
  return (unsigned short)(u >> 16);
}

// ------ Phase 1 (merged): per-(b,s) packed sums (blocks 0..1023) +
//        conv_w fp32->bf16 (blocks 1024..1599) ---------------------------------
__global__ void k_accum_convw(const int* __restrict__ seg,
                              unsigned long long* __restrict__ partials,
                              const float* __restrict__ w,
                              unsigned short* __restrict__ wb) {
  __shared__ unsigned long long ls[S_N];
  const int bid = blockIdx.x;
  const int tid = threadIdx.x;
  if (bid >= 1024) {                 // conv_w conversion: 147,456 float4s
    int idx = (bid - 1024) * 256 + tid;
    float4 v = ((const float4*)w)[idx];
    ushort4 o;
    o.x = f2bf(v.x); o.y = f2bf(v.y); o.z = f2bf(v.z); o.w = f2bf(v.w);
    ((ushort4*)wb)[idx] = o;
    return;
  }
  const int xblk = bid & 15;         // 0..15
  const int b    = bid >> 4;         // 0..63
  for (int i = tid; i < S_N; i += 256) ls[i] = 0ULL;
  __syncthreads();
  const int pix0 = xblk * 16384;
  const int4* segb = (const int4*)(seg + (size_t)b * (H_ * W_) + pix0);
  for (int it = 0; it < 16; ++it) {
    int4 s4 = segb[it * 256 + tid];
    int p0 = pix0 + (it * 256 + tid) * 4;
    unsigned long long base = ((unsigned long long)(unsigned)(p0 >> 9) << 39)
                            | ((unsigned long long)(unsigned)(p0 & (W_ - 1)) << 15)
                            | 1ULL;
    #pragma unroll
    for (int j = 0; j < 4; ++j) {
      int s = (&s4.x)[j];
      s = ((unsigned)s < S_N) ? s : 0;
      atomicAdd(&ls[s], base + ((unsigned long long)j << 15));
    }
  }
  __syncthreads();
  unsigned long long* gp = partials + ((size_t)b * 16 + xblk) * S_N;
  for (int s = tid; s < S_N; s += 256) gp[s] = ls[s];
}

// ------ Phase 2 (merged): per-patch centroid reduce + COALESCED gather --------
__global__ __launch_bounds__(256) void k_patch3(const float* __restrict__ img,
                                                const unsigned long long* __restrict__ partials,
                                                unsigned short* __restrict__ A) {
  const int g  = threadIdx.x >> 4;    // 0..15 : patch slot in block
  const int lx = threadIdx.x & 15;    // x-offset lane
  const int m  = blockIdx.x * 16 + g;
  const int b  = m >> 10;
  const int s  = m & (S_N - 1);
  unsigned long long v = partials[((size_t)b * 16 + lx) * S_N + s];
  unsigned c  = (unsigned)(v & 0x7FFFULL);
  unsigned sx = (unsigned)((v >> 15) & 0xFFFFFFULL);
  unsigned sy = (unsigned)(v >> 39);
  #pragma unroll
  for (int off = 8; off; off >>= 1) {
    c  += __shfl_xor(c,  off, 16);
    sx += __shfl_xor(sx, off, 16);
    sy += __shfl_xor(sy, off, 16);
  }
  int xmin = 0, ymin = 0;
  if (c > 0) {
    float cf = (float)c;
    xmin = (int)floorf((float)sx / cf);   // IEEE f32 div of exact ints == ref
    ymin = (int)floorf((float)sy / cf);
  }
  const int x  = xmin - HALF + lx;
  const int y0 = ymin - HALF;
  const bool xok = (unsigned)x < W_;
  const int xs = xok ? x : 0;
  const float* ib = img + (size_t)b * 3 * H_ * W_;
  unsigned short* Am = A + (size_t)m * K_N + lx;
  #pragma unroll
  for (int r = 0; r < 48; ++r) {      // r = c*16 + h
    const int y = y0 + (r & 15);
    const bool ok = xok && ((unsigned)y < H_);
    const int ys = ((unsigned)y < H_) ? y : 0;
    float pv = ib[(((r >> 4) << 9) + ys) * W_ + xs];
    pv = ok ? pv : 0.f;
    Am[r * 16] = f2bf(pv);
  }
}

// ------ Phase 3: B-STATIONARY BARRIER-FREE GEMM -------------------------------
// The r2-r10 lesson: every barrier-phased schedule pins MfmaUtil at ~26-28%
// because all waves are forced into the same phase with 1 block/CU. Here the
// 64-col B panel (96 KB) is staged into LDS ONCE in FRAGMENT-MAJOR layout
// (slot = frag*64 + lane -> ds_read_b128 is lane-contiguous -> zero bank
// conflicts, no swizzle), then after a single barrier each wave free-runs:
// A loaded global->reg (own rows, L2-hot via XCD locality), MFMA vs LDS B,
// C written per 16-row group (write burst spread through the kernel).
// No inter-wave hazard exists after the barrier -> race-free by construction.
// Grid 1536 = 8 XCD x (16 bm x 12 bn, bn fastest): A panel fetched from HBM
// once, L2 serves the 12x bn reuse.
__global__ __launch_bounds__(512) void k_gemmbs(
    const unsigned short* __restrict__ Amat,
    const unsigned short* __restrict__ Bmat,
    float* __restrict__ out) {
  __shared__ unsigned short Bs[49152];   // 96 KB = 96 frags x 64 lanes x 16 B
  const int tid  = threadIdx.x;
  const int wave = tid >> 6;
  const int lane = tid & 63;

  // bijective XCD remap: 1536 = 8 XCDs x 192; 192 = 16 bm x 12 bn (bn fastest)
  const int virt = (blockIdx.x & 7) * 192 + (blockIdx.x >> 3);
  const int bm = virt / 12;          // 0..127 : 512-row A panel
  const int bn = virt - bm * 12;     // 0..11  : 64-col B panel
  const int gm0 = bm * 512;
  const int gn0 = bn * 64;

  // Stage B panel fragment-major: frag f = nf*24 + kc holds, at lane sl,
  // B[gn0 + nf*16 + (sl&15)][kc*32 + (sl>>4)*8 .. +7]  (16 B per lane).
  for (int i = 0; i < 12; ++i) {
    int slot = i * 512 + tid;          // 0..6143
    int f  = slot >> 6;                // 0..95
    int sl = slot & 63;
    int nf = f / 24;
    int kc = f - nf * 24;
    int col = gn0 + nf * 16 + (sl & 15);
    int k0  = kc * 32 + (sl >> 4) * 8;
    bf16x8 v = *(const bf16x8*)&Bmat[(size_t)col * K_N + k0];
    *(bf16x8*)&Bs[slot * 8] = v;
  }
  __syncthreads();                     // the ONLY barrier

  // Each wave: 64 own rows (4 groups of 16), full 64-col panel.
  const size_t abase = (size_t)(gm0 + wave * 64 + (lane & 15)) * K_N + (lane >> 4) * 8;
  for (int mg = 0; mg < 4; ++mg) {
    const unsigned short* ap = Amat + abase + (size_t)mg * 16 * K_N;
    f32x4 acc0 = {0.f,0.f,0.f,0.f}, acc1 = {0.f,0.f,0.f,0.f};
    f32x4 acc2 = {0.f,0.f,0.f,0.f}, acc3 = {0.f,0.f,0.f,0.f};
    #pragma unroll
    for (int kc = 0; kc < 24; ++kc) {
      bf16x8 a  = *(const bf16x8*)(ap + kc * 32);
      bf16x8 b0 = *(const bf16x8*)&Bs[((0 * 24 + kc) * 64 + lane) * 8];
      bf16x8 b1 = *(const bf16x8*)&Bs[((1 * 24 + kc) * 64 + lane) * 8];
      bf16x8 b2 = *(const bf16x8*)&Bs[((2 * 24 + kc) * 64 + lane) * 8];
      bf16x8 b3 = *(const bf16x8*)&Bs[((3 * 24 + kc) * 64 + lane) * 8];
      acc0 = __builtin_amdgcn_mfma_f32_16x16x32_bf16(a, b0, acc0, 0, 0, 0);
      acc1 = __builtin_amdgcn_mfma_f32_16x16x32_bf16(a, b1, acc1, 0, 0, 0);
      acc2 = __builtin_amdgcn_mfma_f32_16x16x32_bf16(a, b2, acc2, 0, 0, 0);
      acc3 = __builtin_amdgcn_mfma_f32_16x16x32_bf16(a, b3, acc3, 0, 0, 0);
    }
    // C/D layout: col = lane&15, row = (lane>>4)*4 + reg
    const int row0 = gm0 + wave * 64 + mg * 16 + (lane >> 4) * 4;
    const int col0 = gn0 + (lane & 15);
    #pragma unroll
    for (int r = 0; r < 4; ++r) {
      float* orow = out + (size_t)(row0 + r) * E_N + col0;
      orow[0]  = acc0[r];
      orow[16] = acc1[r];
      orow[32] = acc2[r];
      orow[48] = acc3[r];
    }
  }
}

extern "C" void kernel_launch(void* const* d_in, const int* in_sizes, int n_in,
                              void* d_out, int out_size, void* d_ws, size_t ws_size,
                              hipStream_t stream) {
  const float* img = (const float*)d_in[0];
  const int*   seg = (const int*)d_in[1];
  const float* cw  = (const float*)d_in[2];
  float* out = (float*)d_out;
  char* ws = (char*)d_ws;

  unsigned long long* partials = (unsigned long long*)ws;    // 8,388,608 B
  unsigned short* Bmat = (unsigned short*)(ws + 8388608);    // 1,179,648 B
  unsigned short* Amat = (unsigned short*)(ws + 9568256);    // 100,663,296 B

  k_accum_convw<<<1600, 256, 0, stream>>>(seg, partials, cw, Bmat);
  k_patch3<<<4096, 256, 0, stream>>>(img, partials, Amat);
  k_gemmbs<<<1536, 512, 0, stream>>>(Amat, Bmat, out);
}

// Round 13
// 175.784 us; speedup vs baseline: 3.8649x; 3.8649x over previous
//
#include <hip/hip_runtime.h>
#include <hip/hip_bf16.h>
#include <stdint.h>

// Problem constants (fixed by setup_inputs)
#define B_   64
#define H_   512
#define W_   512
#define S_N  1024      // n_segments
#define E_N  768       // embed_dim
#define K_N  768       // C*box*box = 3*16*16
#define HALF 8

typedef short bf16x8 __attribute__((ext_vector_type(8)));
typedef float f32x4  __attribute__((ext_vector_type(4)));

__device__ __forceinline__ unsigned short f2bf(float f) {
  union { float f; unsigned u; } v; v.f = f;
  unsigned u = v.u;
  u += 0x7FFF + ((u >> 16) & 1);   // RNE
  return (unsigned short)(u >> 16);
}

// ------ Phase 1 (merged): per-(b,s) packed sums (blocks 0..1023) +
//        conv_w fp32->bf16 (blocks 1024..1599) ---------------------------------
__global__ void k_accum_convw(const int* __restrict__ seg,
                              unsigned long long* __restrict__ partials,
                              const float* __restrict__ w,
                              unsigned short* __restrict__ wb) {
  __shared__ unsigned long long ls[S_N];
  const int bid = blockIdx.x;
  const int tid = threadIdx.x;
  if (bid >= 1024) {                 // conv_w conversion: 147,456 float4s
    int idx = (bid - 1024) * 256 + tid;
    float4 v = ((const float4*)w)[idx];
    ushort4 o;
    o.x = f2bf(v.x); o.y = f2bf(v.y); o.z = f2bf(v.z); o.w = f2bf(v.w);
    ((ushort4*)wb)[idx] = o;
    return;
  }
  const int xblk = bid & 15;         // 0..15
  const int b    = bid >> 4;         // 0..63
  for (int i = tid; i < S_N; i += 256) ls[i] = 0ULL;
  __syncthreads();
  const int pix0 = xblk * 16384;
  const int4* segb = (const int4*)(seg + (size_t)b * (H_ * W_) + pix0);
  for (int it = 0; it < 16; ++it) {
    int4 s4 = segb[it * 256 + tid];
    int p0 = pix0 + (it * 256 + tid) * 4;
    unsigned long long base = ((unsigned long long)(unsigned)(p0 >> 9) << 39)
                            | ((unsigned long long)(unsigned)(p0 & (W_ - 1)) << 15)
                            | 1ULL;
    #pragma unroll
    for (int j = 0; j < 4; ++j) {
      int s = (&s4.x)[j];
      s = ((unsigned)s < S_N) ? s : 0;
      atomicAdd(&ls[s], base + ((unsigned long long)j << 15));
    }
  }
  __syncthreads();
  unsigned long long* gp = partials + ((size_t)b * 16 + xblk) * S_N;
  for (int s = tid; s < S_N; s += 256) gp[s] = ls[s];
}

// ------ Phase 2 (merged): per-patch centroid reduce + COALESCED gather --------
__global__ __launch_bounds__(256) void k_patch3(const float* __restrict__ img,
                                                const unsigned long long* __restrict__ partials,
                                                unsigned short* __restrict__ A) {
  const int g  = threadIdx.x >> 4;    // 0..15 : patch slot in block
  const int lx = threadIdx.x & 15;    // x-offset lane
  const int m  = blockIdx.x * 16 + g;
  const int b  = m >> 10;
  const int s  = m & (S_N - 1);
  unsigned long long v = partials[((size_t)b * 16 + lx) * S_N + s];
  unsigned c  = (unsigned)(v & 0x7FFFULL);
  unsigned sx = (unsigned)((v >> 15) & 0xFFFFFFULL);
  unsigned sy = (unsigned)(v >> 39);
  #pragma unroll
  for (int off = 8; off; off >>= 1) {
    c  += __shfl_xor(c,  off, 16);
    sx += __shfl_xor(sx, off, 16);
    sy += __shfl_xor(sy, off, 16);
  }
  int xmin = 0, ymin = 0;
  if (c > 0) {
    float cf = (float)c;
    xmin = (int)floorf((float)sx / cf);   // IEEE f32 div of exact ints == ref
    ymin = (int)floorf((float)sy / cf);
  }
  const int x  = xmin - HALF + lx;
  const int y0 = ymin - HALF;
  const bool xok = (unsigned)x < W_;
  const int xs = xok ? x : 0;
  const float* ib = img + (size_t)b * 3 * H_ * W_;
  unsigned short* Am = A + (size_t)m * K_N + lx;
  #pragma unroll
  for (int r = 0; r < 48; ++r) {      // r = c*16 + h
    const int y = y0 + (r & 15);
    const bool ok = xok && ((unsigned)y < H_);
    const int ys = ((unsigned)y < H_) ? y : 0;
    float pv = ib[(((r >> 4) << 9) + ys) * W_ + xs];
    pv = ok ? pv : 0.f;
    Am[r * 16] = f2bf(pv);
  }
}

// ---- Phase 3: 256x256 DOUBLE-BUFFERED simple-loop GEMM (T14 issue-early) -----
// r10's k_gemms (117us) serialized {stage -> vmcnt(0) -> compute} per tile,
// exposing the full L2 round-trip. This variant issues tile k+1's stage BEFORE
// computing tile k (double-buffered LDS), so stage latency hides under the 64
// MFMAs; the vmcnt(0) at tile end only drains the residue. Same proven stage
// partition + T2 both-sides swizzle + fragment reads as r10 (passed) — only
// the issue order and buffer index changed. Hazards: stage(b^1)@tile k issued
// after the sync ending all reads of b^1 (tile k-1) [all waves' ds_reads
// returned before their sync arrival]; vmcnt(0)+sync precede any read of the
// staged buffer; tail stages nothing. 128KB LDS -> 1 block/CU.
__global__ __launch_bounds__(512) void k_gemmd(
    const unsigned short* __restrict__ Amat,
    const unsigned short* __restrict__ Bmat,
    float* __restrict__ out) {
  __shared__ unsigned short As[2][256 * 64];
  __shared__ unsigned short Bs[2][256 * 64];
  const int tid  = threadIdx.x;
  const int wave = tid >> 6;
  const int lane = tid & 63;

  // bijective XCD remap: 768 blocks = 8 XCDs x 96; bn fastest
  const int virt = (blockIdx.x & 7) * 96 + (blockIdx.x >> 3);
  const int bm = virt / 3;
  const int bn = virt - bm * 3;
  const int gm0 = bm * 256;
  const int gn0 = bn * 256;

  const int wr = wave >> 2;          // 0..1 : wave row (128 rows)
  const int wc = wave & 3;           // 0..3 : wave col (64 cols)
  const int rlo  = lane & 15;
  const int rsel = lane & 7;
  const int sub  = lane >> 4;        // 0..3
  int swz[2];
  swz[0] = ((0 + sub) ^ rsel) * 8;   // shorts offset, kk=0
  swz[1] = ((4 + sub) ^ rsel) * 8;   // kk=1

  f32x4 acc[8][4];
  #pragma unroll
  for (int i = 0; i < 8; ++i)
    #pragma unroll
    for (int j = 0; j < 4; ++j)
      acc[i][j] = (f32x4){0.f, 0.f, 0.f, 0.f};

  // Stage a full 256x64 tile (2048 16B segs): 4+4 gload_lds per thread.
  // seg s -> row s>>3, chunk s&7; source chunk pre-XORed with row&7 (T2).
  auto stage = [&](int buf, int k0) {
    #pragma unroll
    for (int i = 0; i < 4; ++i) {
      int seg = i * 512 + tid;
      int row = seg >> 3;
      int csrc = (seg & 7) ^ (row & 7);
      const unsigned short* g = Amat + (size_t)(gm0 + row) * K_N + k0 + csrc * 8;
      __builtin_amdgcn_global_load_lds((const __attribute__((address_space(1))) void*)g,
        (__attribute__((address_space(3))) void*)&As[buf][(i * 512 + wave * 64) * 8], 16, 0, 0);
    }
    #pragma unroll
    for (int i = 0; i < 4; ++i) {
      int seg = i * 512 + tid;
      int row = seg >> 3;
      int csrc = (seg & 7) ^ (row & 7);
      const unsigned short* g = Bmat + (size_t)(gn0 + row) * K_N + k0 + csrc * 8;
      __builtin_amdgcn_global_load_lds((const __attribute__((address_space(1))) void*)g,
        (__attribute__((address_space(3))) void*)&Bs[buf][(i * 512 + wave * 64) * 8], 16, 0, 0);
    }
  };

  // Prologue: tile 0 into buf 0.
  stage(0, 0);
  asm volatile("s_waitcnt vmcnt(0)" ::: "memory");
  __syncthreads();

  for (int kt = 0; kt < 12; ++kt) {
    const int buf = kt & 1;
    if (kt + 1 < 12) stage(buf ^ 1, (kt + 1) * 64);   // issue-early (T14)

    #pragma unroll
    for (int kk = 0; kk < 2; ++kk) {
      bf16x8 av[8], bv[4];
      #pragma unroll
      for (int mi = 0; mi < 8; ++mi)
        av[mi] = *(const bf16x8*)&As[buf][(wr * 128 + mi * 16 + rlo) * 64 + swz[kk]];
      #pragma unroll
      for (int ni = 0; ni < 4; ++ni)
        bv[ni] = *(const bf16x8*)&Bs[buf][(wc * 64 + ni * 16 + rlo) * 64 + swz[kk]];
      __builtin_amdgcn_s_setprio(1);
      #pragma unroll
      for (int mi = 0; mi < 8; ++mi)
        #pragma unroll
        for (int ni = 0; ni < 4; ++ni)
          acc[mi][ni] = __builtin_amdgcn_mfma_f32_16x16x32_bf16(
              av[mi], bv[ni], acc[mi][ni], 0, 0, 0);
      __builtin_amdgcn_s_setprio(0);
    }

    asm volatile("s_waitcnt vmcnt(0)" ::: "memory");  // next tile landed
    __syncthreads();                                  // publish buf^1; all reads of buf done
  }

  // Epilogue: C/D layout col=lane&15, row=(lane>>4)*4+reg
  const int row0 = gm0 + wr * 128 + (lane >> 4) * 4;
  const int col0 = gn0 + wc * 64 + (lane & 15);
  #pragma unroll
  for (int mi = 0; mi < 8; ++mi)
    #pragma unroll
    for (int ni = 0; ni < 4; ++ni)
      #pragma unroll
      for (int r = 0; r < 4; ++r)
        out[(size_t)(row0 + mi * 16 + r) * E_N + (col0 + ni * 16)] = acc[mi][ni][r];
}

extern "C" void kernel_launch(void* const* d_in, const int* in_sizes, int n_in,
                              void* d_out, int out_size, void* d_ws, size_t ws_size,
                              hipStream_t stream) {
  const float* img = (const float*)d_in[0];
  const int*   seg = (const int*)d_in[1];
  const float* cw  = (const float*)d_in[2];
  float* out = (float*)d_out;
  char* ws = (char*)d_ws;

  unsigned long long* partials = (unsigned long long*)ws;    // 8,388,608 B
  unsigned short* Bmat = (unsigned short*)(ws + 8388608);    // 1,179,648 B
  unsigned short* Amat = (unsigned short*)(ws + 9568256);    // 100,663,296 B

  k_accum_convw<<<1600, 256, 0, stream>>>(seg, partials, cw, Bmat);
  k_patch3<<<4096, 256, 0, stream>>>(img, partials, Amat);
  k_gemmd<<<768, 512, 0, stream>>>(Amat, Bmat, out);
}

// Round 14
// 165.950 us; speedup vs baseline: 4.0940x; 1.0593x over previous
//
#include <hip/hip_runtime.h>
#include <hip/hip_bf16.h>
#include <stdint.h>

// Problem constants (fixed by setup_inputs)
#define B_   64
#define H_   512
#define W_   512
#define S_N  1024      // n_segments
#define E_N  768       // embed_dim
#define K_N  768       // C*box*box = 3*16*16
#define HALF 8

typedef short bf16x8 __attribute__((ext_vector_type(8)));
typedef float f32x4  __attribute__((ext_vector_type(4)));
typedef float f32x4u __attribute__((ext_vector_type(4), aligned(4)));  // 4B-aligned float4

__device__ __forceinline__ unsigned short f2bf(float f) {
  union { float f; unsigned u; } v; v.f = f;
  unsigned u = v.u;
  u += 0x7FFF + ((u >> 16) & 1);   // RNE
  return (unsigned short)(u >> 16);
}

// ------ Phase 1 (merged): per-(b,s) packed sums (blocks 0..1023) +
//        conv_w fp32->bf16 (blocks 1024..1599) ---------------------------------
__global__ void k_accum_convw(const int* __restrict__ seg,
                              unsigned long long* __restrict__ partials,
                              const float* __restrict__ w,
                              unsigned short* __restrict__ wb) {
  __shared__ unsigned long long ls[S_N];
  const int bid = blockIdx.x;
  const int tid = threadIdx.x;
  if (bid >= 1024) {                 // conv_w conversion: 147,456 float4s
    int idx = (bid - 1024) * 256 + tid;
    float4 v = ((const float4*)w)[idx];
    ushort4 o;
    o.x = f2bf(v.x); o.y = f2bf(v.y); o.z = f2bf(v.z); o.w = f2bf(v.w);
    ((ushort4*)wb)[idx] = o;
    return;
  }
  const int xblk = bid & 15;         // 0..15
  const int b    = bid >> 4;         // 0..63
  for (int i = tid; i < S_N; i += 256) ls[i] = 0ULL;
  __syncthreads();
  const int pix0 = xblk * 16384;
  const int4* segb = (const int4*)(seg + (size_t)b * (H_ * W_) + pix0);
  for (int it = 0; it < 16; ++it) {
    int4 s4 = segb[it * 256 + tid];
    int p0 = pix0 + (it * 256 + tid) * 4;
    unsigned long long base = ((unsigned long long)(unsigned)(p0 >> 9) << 39)
                            | ((unsigned long long)(unsigned)(p0 & (W_ - 1)) << 15)
                            | 1ULL;
    #pragma unroll
    for (int j = 0; j < 4; ++j) {
      int s = (&s4.x)[j];
      s = ((unsigned)s < S_N) ? s : 0;
      atomicAdd(&ls[s], base + ((unsigned long long)j << 15));
    }
  }
  __syncthreads();
  unsigned long long* gp = partials + ((size_t)b * 16 + xblk) * S_N;
  for (int s = tid; s < S_N; s += 256) gp[s] = ls[s];
}

// ------ Phase 2: centroid reduce + gather, 4-lane x float4 / 8B stores --------
// r13 lesson: patch3's 2B/lane stores (48 instrs) were the waste. Group of 16
// lanes = one patch; lane = (srw = ln>>2 sub-row, x4 = (ln&3)*4). Per iter a
// group covers 4 patch rows: loads dwordx4 (64B/row, same segment efficiency),
// stores ushort4 (group's 4 rows = 128B CONTIGUOUS in Amat). 12 iters vs 48.
// Interior patches (>99.9%: centroids cluster at 255.5 +/- ~9) take the
// unmasked fast path; edge patches take the masked slow path per group.
__global__ __launch_bounds__(256) void k_patch4(const float* __restrict__ img,
                                                const unsigned long long* __restrict__ partials,
                                                unsigned short* __restrict__ A) {
  const int g  = threadIdx.x >> 4;    // 0..15 : patch slot in block
  const int ln = threadIdx.x & 15;
  const int m  = blockIdx.x * 16 + g;
  const int b  = m >> 10;
  const int s  = m & (S_N - 1);
  // centroid: reduce the 16 x-block partials across the 16-lane group
  unsigned long long v = partials[((size_t)b * 16 + ln) * S_N + s];
  unsigned c  = (unsigned)(v & 0x7FFFULL);
  unsigned sx = (unsigned)((v >> 15) & 0xFFFFFFULL);
  unsigned sy = (unsigned)(v >> 39);
  #pragma unroll
  for (int off = 8; off; off >>= 1) {
    c  += __shfl_xor(c,  off, 16);
    sx += __shfl_xor(sx, off, 16);
    sy += __shfl_xor(sy, off, 16);
  }
  int xmin = 0, ymin = 0;
  if (c > 0) {
    float cf = (float)c;
    xmin = (int)floorf((float)sx / cf);   // IEEE f32 div of exact ints == ref
    ymin = (int)floorf((float)sy / cf);
  }
  const int srw = ln >> 2;          // 0..3 : sub-row within 4-row group
  const int x4  = (ln & 3) * 4;     // 0,4,8,12 : x-offset of this lane's float4
  const float* ib = img + (size_t)b * 3 * H_ * W_;
  unsigned short* Am = A + (size_t)m * K_N;

  if (xmin >= HALF && xmin <= W_ - HALF && ymin >= HALF && ymin <= H_ - HALF) {
    // fast path: whole 16x16 window in-bounds, unmasked vector loads
    const float* p0 = ib + (size_t)(ymin - HALF) * W_ + (xmin - HALF);
    #pragma unroll
    for (int r0 = 0; r0 < 12; ++r0) {
      int r = r0 * 4 + srw;               // 0..47 = c*16 + h
      int cch = r >> 4, h = r & 15;
      f32x4u vv = *(const f32x4u*)(p0 + (size_t)((cch << 9) + h) * W_ + x4);
      ushort4 o;
      o.x = f2bf(vv[0]); o.y = f2bf(vv[1]); o.z = f2bf(vv[2]); o.w = f2bf(vv[3]);
      *(ushort4*)(Am + r * 16 + x4) = o;
    }
  } else {
    // slow path: per-element masked (rare)
    #pragma unroll
    for (int r0 = 0; r0 < 12; ++r0) {
      int r = r0 * 4 + srw;
      int cch = r >> 4, h = r & 15;
      int y = ymin - HALF + h;
      bool yok = (unsigned)y < H_;
      const float* rp = ib + (size_t)((cch << 9) + (yok ? y : 0)) * W_;
      ushort4 o;
      unsigned short* op = (unsigned short*)&o;
      #pragma unroll
      for (int j = 0; j < 4; ++j) {
        int x = xmin - HALF + x4 + j;
        float pv = (yok && (unsigned)x < W_) ? rp[x] : 0.f;
        op[j] = f2bf(pv);
      }
      *(ushort4*)(Am + r * 16 + x4) = o;
    }
  }
}

// ------ Phase 3: 256x256 8-phase bf16 MFMA GEMM (best measured: 111.5us),
//        tail peeled with vmcnt(0) ---------------------------------------------
__global__ __launch_bounds__(512) void k_gemm8(
    const unsigned short* __restrict__ Amat,
    const unsigned short* __restrict__ Bmat,
    float* __restrict__ out) {
  __shared__ unsigned short As[2][256 * 64];
  __shared__ unsigned short Bs[2][256 * 64];
  const int tid  = threadIdx.x;
  const int wave = tid >> 6;
  const int lane = tid & 63;

  // bijective XCD remap: 768 blocks = 8 XCDs x 96
  const int virt = (blockIdx.x & 7) * 96 + (blockIdx.x >> 3);
  const int bm = virt / 3;
  const int bn = virt - bm * 3;
  const int gm0 = bm * 256;
  const int gn0 = bn * 256;

  const int wr = wave >> 2;          // 0..1
  const int wc = wave & 3;           // 0..3
  const int rlo  = lane & 15;
  const int rsel = lane & 7;
  const int sub  = lane >> 4;        // 0..3
  int swz[2];
  swz[0] = ((0 + sub) ^ rsel) * 8;   // shorts offset, kk=0
  swz[1] = ((4 + sub) ^ rsel) * 8;   // kk=1

  const int srow = lane >> 3;             // row within 8-row group
  const int sch  = (lane & 7) ^ srow;     // pre-swizzled source chunk

  f32x4 acc[8][4];
  #pragma unroll
  for (int i = 0; i < 8; ++i)
    #pragma unroll
    for (int j = 0; j < 4; ++j)
      acc[i][j] = (f32x4){0.f, 0.f, 0.f, 0.f};

  auto stageA = [&](int buf, int mh, int k0) {
    #pragma unroll
    for (int l = 0; l < 2; ++l) {
      int idx = wave * 2 + l;                                // 0..15
      int rowbase = mh * 64 + (idx >> 3) * 128 + (idx & 7) * 8;
      const unsigned short* g = Amat + (size_t)(gm0 + rowbase + srow) * K_N + k0 + sch * 8;
      __builtin_amdgcn_global_load_lds((const __attribute__((address_space(1))) void*)g,
        (__attribute__((address_space(3))) void*)&As[buf][rowbase * 64], 16, 0, 0);
    }
  };
  auto stageB = [&](int buf, int nh, int k0) {
    #pragma unroll
    for (int l = 0; l < 2; ++l) {
      int idx = wave * 2 + l;
      int rowbase = (idx >> 2) * 64 + nh * 32 + (idx & 3) * 8;
      const unsigned short* g = Bmat + (size_t)(gn0 + rowbase + srow) * K_N + k0 + sch * 8;
      __builtin_amdgcn_global_load_lds((const __attribute__((address_space(1))) void*)g,
        (__attribute__((address_space(3))) void*)&Bs[buf][rowbase * 64], 16, 0, 0);
    }
  };

  bf16x8 a[4][2], b[2][2];

#define LOAD_A(BUF, MH) \
  _Pragma("unroll") for (int mi = 0; mi < 4; ++mi) \
  _Pragma("unroll") for (int kk = 0; kk < 2; ++kk) \
    a[mi][kk] = *(const bf16x8*)&As[BUF][(wr * 128 + (MH) * 64 + mi * 16 + rlo) * 64 + swz[kk]];
#define LOAD_B(BUF, NH) \
  _Pragma("unroll") for (int ni = 0; ni < 2; ++ni) \
  _Pragma("unroll") for (int kk = 0; kk < 2; ++kk) \
    b[ni][kk] = *(const bf16x8*)&Bs[BUF][(wc * 64 + (NH) * 32 + ni * 16 + rlo) * 64 + swz[kk]];
#define MFMA_Q(MI0, NI0) \
  __builtin_amdgcn_s_setprio(1); \
  _Pragma("unroll") for (int mi = 0; mi < 4; ++mi) \
  _Pragma("unroll") for (int ni = 0; ni < 2; ++ni) \
  _Pragma("unroll") for (int kk = 0; kk < 2; ++kk) \
    acc[(MI0) + mi][(NI0) + ni] = __builtin_amdgcn_mfma_f32_16x16x32_bf16( \
        a[mi][kk], b[ni][kk], acc[(MI0) + mi][(NI0) + ni], 0, 0, 0); \
  __builtin_amdgcn_s_setprio(0);
#define SYNC_MFMA \
  __builtin_amdgcn_s_barrier(); \
  asm volatile("s_waitcnt lgkmcnt(0)" ::: "memory"); \
  __builtin_amdgcn_sched_barrier(0);
#define ENDPH __builtin_amdgcn_s_barrier();

  // Prologue: tile0 fully into buf0; tile1's hA0,hB1 into buf1 (staged last).
  stageA(0, 0, 0); stageA(0, 1, 0); stageB(0, 0, 0); stageB(0, 1, 0);
  stageA(1, 0, 64); stageB(1, 1, 64);
  asm volatile("s_waitcnt vmcnt(4)" ::: "memory");   // buf0 landed
  __builtin_amdgcn_s_barrier();

  // Main: 5 iters cover tiles 0..9; all stages unconditional (kD <= 11*64).
  for (int i = 0; i < 5; ++i) {
    const int kB = (2 * i + 1) * 64;
    const int kC = (2 * i + 2) * 64;
    const int kD = (2 * i + 3) * 64;
    // P1: Q1 of tile 2i (buf0)
    LOAD_A(0, 0); LOAD_B(0, 0);
    stageB(1, 0, kB);
    SYNC_MFMA; MFMA_Q(0, 0); ENDPH;
    // P2
    LOAD_B(0, 1);
    stageA(1, 1, kB);
    SYNC_MFMA; MFMA_Q(0, 2); ENDPH;
    // P3
    LOAD_A(0, 1);
    stageA(0, 0, kC);
    SYNC_MFMA; MFMA_Q(4, 2); ENDPH;
    // P4
    LOAD_B(0, 0);
    stageB(0, 1, kC);
    asm volatile("s_waitcnt vmcnt(4)" ::: "memory");  // tile 2i+1 fully landed
    SYNC_MFMA; MFMA_Q(4, 0); ENDPH;
    // P5: Q1 of tile 2i+1 (buf1)
    LOAD_A(1, 0); LOAD_B(1, 0);
    stageB(0, 0, kC);
    SYNC_MFMA; MFMA_Q(0, 0); ENDPH;
    // P6
    LOAD_B(1, 1);
    stageA(0, 1, kC);
    SYNC_MFMA; MFMA_Q(0, 2); ENDPH;
    // P7
    LOAD_A(1, 1);
    stageA(1, 0, kD);
    SYNC_MFMA; MFMA_Q(4, 2); ENDPH;
    // P8
    LOAD_B(1, 0);
    stageB(1, 1, kD);
    asm volatile("s_waitcnt vmcnt(4)" ::: "memory");  // tile 2i+2 fully landed
    SYNC_MFMA; MFMA_Q(4, 0); ENDPH;
  }

  // Tail: tiles 10 (buf0), 11 (buf1). Remaining stages: B11.h0 (T1), A11.h1 (T2).
  {
    const int k11 = 11 * 64;
    // T1
    LOAD_A(0, 0); LOAD_B(0, 0);
    stageB(1, 0, k11);
    SYNC_MFMA; MFMA_Q(0, 0); ENDPH;
    // T2
    LOAD_B(0, 1);
    stageA(1, 1, k11);
    SYNC_MFMA; MFMA_Q(0, 2); ENDPH;
    // T3
    LOAD_A(0, 1);
    SYNC_MFMA; MFMA_Q(4, 2); ENDPH;
    // T4: FULL drain — all tile-11 halves (iter4 P7/P8 + T1/T2) must land.
    LOAD_B(0, 0);
    asm volatile("s_waitcnt vmcnt(0)" ::: "memory");
    SYNC_MFMA; MFMA_Q(4, 0); ENDPH;
    // T5
    LOAD_A(1, 0); LOAD_B(1, 0);
    SYNC_MFMA; MFMA_Q(0, 0); ENDPH;
    // T6
    LOAD_B(1, 1);
    SYNC_MFMA; MFMA_Q(0, 2); ENDPH;
    // T7
    LOAD_A(1, 1);
    SYNC_MFMA; MFMA_Q(4, 2); ENDPH;
    // T8
    LOAD_B(1, 0);
    SYNC_MFMA; MFMA_Q(4, 0); ENDPH;
  }

  // Epilogue: C/D layout col=lane&15, row=(lane>>4)*4+reg
  const int row0 = gm0 + wr * 128 + (lane >> 4) * 4;
  const int col0 = gn0 + wc * 64 + (lane & 15);
  #pragma unroll
  for (int mi = 0; mi < 8; ++mi)
    #pragma unroll
    for (int ni = 0; ni < 4; ++ni)
      #pragma unroll
      for (int r = 0; r < 4; ++r)
        out[(size_t)(row0 + mi * 16 + r) * E_N + (col0 + ni * 16)] = acc[mi][ni][r];
#undef LOAD_A
#undef LOAD_B
#undef MFMA_Q
#undef SYNC_MFMA
#undef ENDPH
}

extern "C" void kernel_launch(void* const* d_in, const int* in_sizes, int n_in,
                              void* d_out, int out_size, void* d_ws, size_t ws_size,
                              hipStream_t stream) {
  const float* img = (const float*)d_in[0];
  const int*   seg = (const int*)d_in[1];
  const float* cw  = (const float*)d_in[2];
  float* out = (float*)d_out;
  char* ws = (char*)d_ws;

  unsigned long long* partials = (unsigned long long*)ws;    // 8,388,608 B
  unsigned short* Bmat = (unsigned short*)(ws + 8388608);    // 1,179,648 B
  unsigned short* Amat = (unsigned short*)(ws + 9568256);    // 100,663,296 B

  k_accum_convw<<<1600, 256, 0, stream>>>(seg, partials, cw, Bmat);
  k_patch4<<<4096, 256, 0, stream>>>(img, partials, Amat);
  k_gemm8<<<768, 512, 0, stream>>>(Amat, Bmat, out);
}